// Round 5
// baseline (1896.068 us; speedup 1.0000x reference)
//
#include <hip/hip_runtime.h>
#include <hip/hip_bf16.h>
#include <math.h>

// Model constants
#define PP 32      // patch
#define OO 128     // outputs per patch
#define QQ 10      // quantiles
#define MM 4       // AR patches per step
#define LL 8       // layers
#define HH 16      // heads
#define HD 64      // head dim
#define DD 1024    // D = H*HD
#define DFF 4096
#define NPATCH 16  // context patches (512/32)
#define B2 64      // 32 batches x {+x, -x}
#define CMAX 20    // max cache length
#define EPSF 1e-6f

typedef __attribute__((ext_vector_type(8))) short s16x8;   // 8 bf16 (4 VGPRs)
typedef __attribute__((ext_vector_type(4))) float f32x4;   // MFMA accumulator
typedef __hip_bfloat16 bf16;

__device__ inline float b2f(short u)
{
    return __uint_as_float(((unsigned)(unsigned short)u) << 16);
}

// Async global->LDS, 16 B per lane. LDS dest = wave-uniform base + lane*16.
__device__ inline void ld_lds16(void* lds_base, const void* gaddr)
{
    __builtin_amdgcn_global_load_lds(
        (const __attribute__((address_space(1))) unsigned int*)gaddr,
        (__attribute__((address_space(3))) unsigned int*)lds_base, 16, 0, 0);
}

// ---------------------------------------------------------------------------
// Running stats (Chan update), context: 16 patches from scratch. Also is_pos.
__global__ void stats_ctx_kernel(const float* __restrict__ x, float* __restrict__ ctx_mu,
                                 float* __restrict__ ctx_sg, float* __restrict__ ispos,
                                 float* __restrict__ normed)
{
    int b2 = blockIdx.x;            // 0..63
    int tid = threadIdx.x;          // 64
    float sign = (b2 < 32) ? 1.f : -1.f;
    const float* xp = x + (size_t)(b2 & 31) * 512;
    __shared__ float smu[NPATCH], ssg[NPATCH];
    if (tid == 0) {
        float n = 0.f, mu = 0.f, sg = 0.f;
        for (int t = 0; t < NPATCH; t++) {
            float s1 = 0.f;
            for (int p = 0; p < PP; p++) s1 += sign * xp[t * PP + p];
            float nn2 = n + 32.f;
            float nmu_ = (n * mu + s1) / nn2;
            float m2 = n * sg * sg;
            for (int p = 0; p < PP; p++) {
                float xv = sign * xp[t * PP + p];
                m2 += (xv - mu) * (xv - nmu_);
            }
            sg = sqrtf(fmaxf(m2 / nn2, 1e-12f));
            mu = nmu_; n = nn2;
            smu[t] = mu; ssg[t] = sg;
            ctx_mu[b2 * NPATCH + t] = mu;
            ctx_sg[b2 * NPATCH + t] = sg;
        }
        if (b2 < 32) {
            int ok = 1;
            for (int i = 0; i < 512; i++) if (xp[i] < 0.f) ok = 0;
            ispos[b2] = (float)ok;
        }
    }
    __syncthreads();
    for (int i = tid; i < 512; i += 64) {
        int t = i >> 5;
        normed[(size_t)b2 * 512 + i] = (sign * xp[i] - smu[t]) / (ssg[t] + EPSF);
    }
}

// AR stats: continue from n=512 state with 4 new patches (= last 128 preds).
__global__ void stats_ar_kernel(const float* __restrict__ lastc, const float* __restrict__ ctx_mu,
                                const float* __restrict__ ctx_sg, float* __restrict__ nmu,
                                float* __restrict__ nsg, float* __restrict__ normed)
{
    int b2 = blockIdx.x;
    int tid = threadIdx.x;
    __shared__ float smu[MM], ssg[MM];
    const float* xp = lastc + (size_t)b2 * 128;
    if (tid == 0) {
        float n = 512.f;
        float mu = ctx_mu[b2 * NPATCH + 15];
        float sg = ctx_sg[b2 * NPATCH + 15];
        for (int t = 0; t < MM; t++) {
            float s1 = 0.f;
            for (int p = 0; p < PP; p++) s1 += xp[t * PP + p];
            float nn2 = n + 32.f;
            float nmu_ = (n * mu + s1) / nn2;
            float m2 = n * sg * sg;
            for (int p = 0; p < PP; p++) {
                float xv = xp[t * PP + p];
                m2 += (xv - mu) * (xv - nmu_);
            }
            sg = sqrtf(fmaxf(m2 / nn2, 1e-12f));
            mu = nmu_; n = nn2;
            smu[t] = mu; ssg[t] = sg;
            nmu[b2 * MM + t] = mu;
            nsg[b2 * MM + t] = sg;
        }
    }
    __syncthreads();
    for (int i = tid; i < 128; i += 64) {
        int t = i >> 5;
        normed[(size_t)b2 * 128 + i] = (xp[i] - smu[t]) / (ssg[t] + EPSF);
    }
}

// ---------------------------------------------------------------------------
// Embedding: hdd[row, :] = normed[row, 0:32] @ W_in[0:32, :] + b_in   (fp32)
__global__ __launch_bounds__(256) void embed_kernel(const float* __restrict__ normed,
                                                    const float* __restrict__ Win,
                                                    const float* __restrict__ bin,
                                                    float* __restrict__ hdd)
{
    int row = blockIdx.x;
    int tid = threadIdx.x;
    __shared__ float p[PP];
    if (tid < PP) p[tid] = normed[(size_t)row * PP + tid];
    __syncthreads();
    for (int c = tid; c < DD; c += 256) {
        float s = bin[c];
        for (int k = 0; k < PP; k++) s = fmaf(p[k], Win[k * DD + c], s);
        hdd[(size_t)row * DD + c] = s;
    }
}

// ---------------------------------------------------------------------------
// LayerNorm: wave-per-row, fp32 in -> bf16 out. Grid = R/4 blocks of 256.
__global__ __launch_bounds__(256) void layernorm_kernel(const float* __restrict__ in,
                                                        bf16* __restrict__ out,
                                                        const float* __restrict__ scale)
{
    int wave = threadIdx.x >> 6, lane = threadIdx.x & 63;
    size_t row = (size_t)blockIdx.x * 4 + wave;
    const float* x = in + row * DD + lane * 16;
    float e[16];
    #pragma unroll
    for (int j = 0; j < 4; j++) {
        float4 t = ((const float4*)x)[j];
        e[4 * j] = t.x; e[4 * j + 1] = t.y; e[4 * j + 2] = t.z; e[4 * j + 3] = t.w;
    }
    float s = 0.f;
    #pragma unroll
    for (int i = 0; i < 16; i++) s += e[i];
    #pragma unroll
    for (int o = 32; o > 0; o >>= 1) s += __shfl_xor(s, o, 64);
    float m = s * (1.f / 1024.f);
    float vv = 0.f;
    #pragma unroll
    for (int i = 0; i < 16; i++) { float d = e[i] - m; vv = fmaf(d, d, vv); }
    #pragma unroll
    for (int o = 32; o > 0; o >>= 1) vv += __shfl_xor(vv, o, 64);
    float inv = rsqrtf(vv * (1.f / 1024.f) + EPSF);
    const float* sc = scale + lane * 16;
    union { bf16 b[16]; s16x8 v2[2]; } ob;
    #pragma unroll
    for (int j = 0; j < 4; j++) {
        float4 t = ((const float4*)sc)[j];
        ob.b[4 * j]     = __float2bfloat16((e[4 * j]     - m) * inv * t.x);
        ob.b[4 * j + 1] = __float2bfloat16((e[4 * j + 1] - m) * inv * t.y);
        ob.b[4 * j + 2] = __float2bfloat16((e[4 * j + 2] - m) * inv * t.z);
        ob.b[4 * j + 3] = __float2bfloat16((e[4 * j + 3] - m) * inv * t.w);
    }
    s16x8* op = (s16x8*)(out + row * DD + lane * 16);
    op[0] = ob.v2[0]; op[1] = ob.v2[1];
}

// ---------------------------------------------------------------------------
// Weight transpose: fp32 [R][C] (layer blockIdx.z) -> bf16 [C][R]
__global__ __launch_bounds__(256) void transpose_w(const float* __restrict__ in,
                                                   bf16* __restrict__ out,
                                                   int R, int C)
{
    __shared__ float t[32][33];
    size_t base = (size_t)blockIdx.z * R * C;
    int c0 = blockIdx.x * 32, r0 = blockIdx.y * 32;
    int tx = threadIdx.x & 31, ty = threadIdx.x >> 5;  // 32 x 8
    #pragma unroll
    for (int s = 0; s < 4; s++)
        t[ty + 8 * s][tx] = in[base + (size_t)(r0 + ty + 8 * s) * C + c0 + tx];
    __syncthreads();
    #pragma unroll
    for (int s = 0; s < 4; s++)
        out[base + (size_t)(c0 + ty + 8 * s) * R + r0 + tx] = __float2bfloat16(t[tx][ty + 8 * s]);
}

// Gather Wout quantile-5 columns: w5T[o][k] = Wout[k][o*10+5], bf16
__global__ void w5_kernel(const float* __restrict__ Wout, bf16* __restrict__ w5T)
{
    int i = blockIdx.x * 256 + threadIdx.x;   // 128*1024
    int o = i >> 10, k = i & 1023;
    w5T[i] = __float2bfloat16(Wout[(size_t)k * (OO * QQ) + o * QQ + 5]);
}

// ---------------------------------------------------------------------------
__device__ inline float gelu_tanh(float x)
{
    float x3 = x * x * x;
    float t = tanhf(0.7978845608028654f * (x + 0.044715f * x3));
    return 0.5f * x * (1.f + t);
}

// bf16 MFMA GEMM, BK=64, DOUBLE-BUFFERED (2-phase): stage(t+1) issued before
// compute(t); the compiler's pre-barrier vmcnt(0) drain is thus overlapped
// with a full compute phase. One barrier per K-step. LDS = same bytes as the
// single-buffered BK=128 version -> occupancy unchanged. XOR-swizzled LDS
// (granule g at row r holds global granule g^(r&7); read applies the same
// involution -> conflict-free ds_read_b128). C[M,N] = A[M,K] @ BT[N,K]^T.
// Requires Kpart % 64 == 0.
// EP: 0 = store fp32 (atomicAdd if gridDim.z>1); 1 = gelu -> bf16;
//     2 = atomicAdd (residual); 3 = QKV: cols<DD -> fp32 Q (stride DD),
//         else bf16 direct into K/V caches (requires gridDim.z==1).
template<int BM, int BN, int EP>
__global__ __launch_bounds__(256) void hgemm(const bf16* __restrict__ A,
                                             const bf16* __restrict__ BT,
                                             float* __restrict__ C,
                                             bf16* __restrict__ Cbf,
                                             bf16* __restrict__ Kc,
                                             bf16* __restrict__ Vc,
                                             int M, int N, int K, int Kpart,
                                             int nn, int koff)
{
    constexpr int FM = BM / 32 > 0 ? BM / 32 : 1;   // BM=32 -> FM=1
    constexpr int FN = BN / 32;
    __shared__ __align__(16) short As[2][BM * 64];  // [BM][64] bf16, rows = 128 B
    __shared__ __align__(16) short Bs[2][BN * 64];
    int tid = threadIdx.x;
    int lane = tid & 63, wave = tid >> 6;
    int wm = (wave >> 1) * (BM / 2), wn = (wave & 1) * (BN / 2);
    int lm = lane & 15, quad = lane >> 4;
    int row0 = blockIdx.y * BM, col0 = blockIdx.x * BN;
    int kb = blockIdx.z * Kpart;
    int nt = Kpart >> 6;              // K-steps of 64
    int r8 = lane >> 3;               // row within 8-row chunk
    int gsw = ((lane & 7) ^ r8) * 8;  // pre-swizzled source k-offset (shorts)
    int swz = lm & 7;                 // read-side row swizzle key

    auto stage = [&](int buf, int k0) {
        #pragma unroll
        for (int c = 0; c < BM / 32; c++) {
            int ch = wave + 4 * c;    // 8 rows, 1 KB per wave
            ld_lds16(&As[buf][ch * 512], A + (size_t)(row0 + ch * 8 + r8) * K + k0 + gsw);
        }
        #pragma unroll
        for (int c = 0; c < BN / 32; c++) {
            int ch = wave + 4 * c;
            ld_lds16(&Bs[buf][ch * 512], BT + (size_t)(col0 + ch * 8 + r8) * K + k0 + gsw);
        }
    };

    f32x4 ac[FM][FN];
    #pragma unroll
    for (int i = 0; i < FM; i++)
        #pragma unroll
        for (int j = 0; j < FN; j++) ac[i][j] = (f32x4){0.f, 0.f, 0.f, 0.f};

    stage(0, kb);
    __syncthreads();                  // cold-start drain (only unhidden one)

    for (int t = 0; t < nt; ++t) {
        if (t + 1 < nt) stage((t + 1) & 1, kb + (t + 1) * 64);  // overlap w/ compute
        int cur = t & 1;
        #pragma unroll
        for (int kk = 0; kk < 2; kk++) {
            int gq = ((kk * 4 + quad) ^ swz) * 8;
            s16x8 af[FM], bfr[FN];
            #pragma unroll
            for (int i = 0; i < FM; i++) af[i] = *(const s16x8*)&As[cur][(wm + i * 16 + lm) * 64 + gq];
            #pragma unroll
            for (int j = 0; j < FN; j++) bfr[j] = *(const s16x8*)&Bs[cur][(wn + j * 16 + lm) * 64 + gq];
            #pragma unroll
            for (int i = 0; i < FM; i++)
                #pragma unroll
                for (int j = 0; j < FN; j++)
                    ac[i][j] = __builtin_amdgcn_mfma_f32_16x16x32_bf16(af[i], bfr[j], ac[i][j], 0, 0, 0);
        }
        __syncthreads();              // drains next-tile loads (post-overlap) +
                                      // guards buf[cur] for overwrite at t+1
    }
    bool multi = (gridDim.z > 1);
    #pragma unroll
    for (int i = 0; i < FM; i++) {
        #pragma unroll
        for (int j = 0; j < FN; j++) {
            #pragma unroll
            for (int r = 0; r < 4; r++) {
                int rr = row0 + wm + i * 16 + quad * 4 + r;
                int cc = col0 + wn + j * 16 + lm;
                float v = ac[i][j][r];
                if (EP == 0) {
                    size_t idx = (size_t)rr * N + cc;
                    if (multi) atomicAdd(&C[idx], v); else C[idx] = v;
                } else if (EP == 1) {
                    Cbf[(size_t)rr * N + cc] = __float2bfloat16(gelu_tanh(v));
                } else if (EP == 2) {
                    atomicAdd(&C[(size_t)rr * N + cc], v);
                } else {
                    // QKV fused scatter (tile is uniformly Q, K, or V: 1024%BN==0)
                    if (cc < DD) {
                        C[(size_t)rr * DD + cc] = v;          // Q, fp32, stride DD
                    } else {
                        int col = cc & (DD - 1);
                        int b = rr / nn, n = rr - b * nn;
                        int h = col >> 6, hd_ = col & 63;
                        size_t dst = (((size_t)(b * HH + h)) * CMAX + koff + n) * HD + hd_;
                        if (cc < 2 * DD) Kc[dst] = __float2bfloat16(v);
                        else             Vc[dst] = __float2bfloat16(v);
                    }
                }
            }
        }
    }
}

// ---------------------------------------------------------------------------
// Attention: 4 waves per block, one (b,h,n) task per wave. Causal over
// len = n + off + 1 cache rows. Q fp32, row stride DD.
__global__ __launch_bounds__(256) void attn_kernel(const float* __restrict__ qb,
                                                   const bf16* __restrict__ Kc,
                                                   const bf16* __restrict__ Vc,
                                                   bf16* __restrict__ outb, int Nn, int off)
{
    int wave = threadIdx.x >> 6, lane = threadIdx.x & 63;
    int gid = blockIdx.x * 4 + wave;
    int n = gid % Nn;
    int h = (gid / Nn) & (HH - 1);
    int b = gid / (Nn * HH);
    int len = n + off + 1;
    const float* q = qb + ((size_t)(b * Nn + n)) * DD + h * HD;
    const bf16* Kb = Kc + ((size_t)(b * HH + h)) * CMAX * HD;
    const bf16* Vb = Vc + ((size_t)(b * HH + h)) * CMAX * HD;

    __shared__ float sq[4][64];
    __shared__ float satt[4][64];
    sq[wave][lane] = q[lane];
    __syncthreads();

    float score = -1e30f;
    if (lane < len) {
        const s16x8* kr8 = (const s16x8*)(Kb + lane * HD);
        float s = 0.f;
        #pragma unroll
        for (int c = 0; c < 8; c++) {
            s16x8 kv = kr8[c];
            #pragma unroll
            for (int j = 0; j < 8; j++) s = fmaf(sq[wave][c * 8 + j], b2f(kv[j]), s);
        }
        score = s * 0.125f;   // 1/sqrt(64)
    }
    float mx = score;
    for (int o = 32; o > 0; o >>= 1) mx = fmaxf(mx, __shfl_xor(mx, o, 64));
    float e = (lane < len) ? expf(score - mx) : 0.f;
    float sm = e;
    for (int o = 32; o > 0; o >>= 1) sm += __shfl_xor(sm, o, 64);
    satt[wave][lane] = e / sm;
    __syncthreads();
    float acc = 0.f;
    for (int m = 0; m < len; m++) acc = fmaf(satt[wave][m], __bfloat162float(Vb[m * HD + lane]), acc);
    outb[((size_t)(b * Nn + n)) * DD + h * HD + lane] = __float2bfloat16(acc);
}

// ---------------------------------------------------------------------------
// Fused final LN + quantile-5 head + revin. Only the LAST row per b2 is
// consumed downstream, so LN runs on 64 rows instead of R. One block per b2.
__global__ __launch_bounds__(128) void lnout5_kernel(const float* __restrict__ hdd,
                                                     const float* __restrict__ lnf,
                                                     const bf16* __restrict__ w5T,
                                                     const float* __restrict__ mus,
                                                     const float* __restrict__ sgs,
                                                     float* __restrict__ last, int Nn)
{
    int b2 = blockIdx.x, tid = threadIdx.x;
    const float* x = hdd + (size_t)(b2 * Nn + Nn - 1) * DD;
    __shared__ float sx[DD];
    __shared__ float red[128];
    float s = 0.f;
    for (int i = tid; i < DD; i += 128) s += x[i];
    red[tid] = s; __syncthreads();
    for (int st = 64; st > 0; st >>= 1) { if (tid < st) red[tid] += red[tid + st]; __syncthreads(); }
    float m = red[0] * (1.f / 1024.f);
    __syncthreads();
    float vv = 0.f;
    for (int i = tid; i < DD; i += 128) { float d = x[i] - m; vv = fmaf(d, d, vv); }
    red[tid] = vv; __syncthreads();
    for (int st = 64; st > 0; st >>= 1) { if (tid < st) red[tid] += red[tid + st]; __syncthreads(); }
    float inv = rsqrtf(red[0] * (1.f / 1024.f) + EPSF);
    __syncthreads();
    for (int i = tid; i < DD; i += 128) sx[i] = (x[i] - m) * inv * lnf[i];
    __syncthreads();
    const s16x8* w8 = (const s16x8*)(w5T + (size_t)tid * DD);
    float acc = 0.f;
    for (int k = 0; k < DD / 8; k++) {
        s16x8 wv = w8[k];
        #pragma unroll
        for (int j = 0; j < 8; j++) acc = fmaf(sx[k * 8 + j], b2f(wv[j]), acc);
    }
    float mu = mus[b2 * Nn + (Nn - 1)];
    float sg = sgs[b2 * Nn + (Nn - 1)];
    last[(size_t)b2 * 128 + tid] = acc * (sg + EPSF) + mu;
}

// ---------------------------------------------------------------------------
// Combine +x / -x halves, clamp if all-positive input, emit FLOAT32.
__global__ void combine_kernel(const float* __restrict__ lastc, const float* __restrict__ lasta,
                               const float* __restrict__ ispos, float* __restrict__ out)
{
    int i = blockIdx.x * 256 + threadIdx.x;   // 8192
    int b = i >> 8, t = i & 255;
    float a, an;
    if (t < 128) { a = lastc[b * 128 + t];        an = lastc[(b + 32) * 128 + t]; }
    else         { a = lasta[b * 128 + t - 128];  an = lasta[(b + 32) * 128 + t - 128]; }
    float raw = (a - an) * 0.5f;
    if (ispos[b] > 0.5f) raw = fmaxf(raw, 0.f);
    out[i] = raw;
}

// ---------------------------------------------------------------------------
extern "C" void kernel_launch(void* const* d_in, const int* in_sizes, int n_in,
                              void* d_out, int out_size, void* d_ws, size_t ws_size,
                              hipStream_t stream)
{
    (void)in_sizes; (void)n_in; (void)out_size;
    const float* x     = (const float*)d_in[0];
    const float* W_in  = (const float*)d_in[1];
    const float* b_in  = (const float*)d_in[2];
    const float* ln1_s = (const float*)d_in[3];
    const float* Wqkv  = (const float*)d_in[4];   // (8,1024,3072)
    const float* Wo    = (const float*)d_in[5];   // (8,1024,1024)
    const float* ln2_s = (const float*)d_in[6];
    const float* W1    = (const float*)d_in[7];   // (8,1024,4096)
    const float* W2    = (const float*)d_in[8];   // (8,4096,1024)
    const float* lnf_s = (const float*)d_in[9];
    const float* Wout  = (const float*)d_in[10];  // (1024,1280)
    float* out = (float*)d_out;

    size_t off = 0;
    auto alloc = [&](size_t bytes) {
        char* p = (char*)d_ws + off;
        off = (off + bytes + 255) & ~(size_t)255;
        return (void*)p;
    };
    float* ctx_mu = (float*)alloc(B2 * NPATCH * 4);
    float* ctx_sg = (float*)alloc(B2 * NPATCH * 4);
    float* nmu    = (float*)alloc(B2 * MM * 4);
    float* nsg    = (float*)alloc(B2 * MM * 4);
    float* ispos  = (float*)alloc(32 * 4);
    float* normed = (float*)alloc(B2 * NPATCH * PP * 4);
    float* lastc  = (float*)alloc(B2 * 128 * 4);
    float* lasta  = (float*)alloc(B2 * 128 * 4);
    float* hdd    = (float*)alloc((size_t)B2 * NPATCH * DD * 4);
    float* qb     = (float*)alloc((size_t)B2 * NPATCH * DD * 4);   // Q only, fp32
    bf16* xn      = (bf16*)alloc((size_t)B2 * NPATCH * DD * 2);
    bf16* attnb   = (bf16*)alloc((size_t)B2 * NPATCH * DD * 2);
    bf16* ffnb    = (bf16*)alloc((size_t)B2 * NPATCH * DFF * 2);
    const size_t cache_l = (size_t)B2 * HH * CMAX * HD;
    bf16* kcache  = (bf16*)alloc(LL * cache_l * 2);
    bf16* vcache  = (bf16*)alloc(LL * cache_l * 2);
    bf16* w5T     = (bf16*)alloc((size_t)OO * DD * 2);

    const size_t szQKV = (size_t)DD * 3 * DD;     // per-layer elems
    const size_t szWO  = (size_t)DD * DD;
    const size_t szW1  = (size_t)DD * DFF;
    const size_t szW2  = (size_t)DFF * DD;
    const size_t WBYTES = (szQKV + szWO + szW1 + szW2) * LL * 2 + 4096;
    bool big = (off + WBYTES) <= ws_size;

    bf16 *wqkvT = nullptr, *woT = nullptr, *w1T = nullptr, *w2T = nullptr, *rot = nullptr;
    if (big) {
        wqkvT = (bf16*)alloc(LL * szQKV * 2);
        woT   = (bf16*)alloc(LL * szWO * 2);
        w1T   = (bf16*)alloc(LL * szW1 * 2);
        w2T   = (bf16*)alloc(LL * szW2 * 2);
        transpose_w<<<dim3(3072 / 32, 1024 / 32, LL), 256, 0, stream>>>(Wqkv, wqkvT, 1024, 3072);
        transpose_w<<<dim3(1024 / 32, 1024 / 32, LL), 256, 0, stream>>>(Wo, woT, 1024, 1024);
        transpose_w<<<dim3(4096 / 32, 1024 / 32, LL), 256, 0, stream>>>(W1, w1T, 1024, 4096);
        transpose_w<<<dim3(1024 / 32, 4096 / 32, LL), 256, 0, stream>>>(W2, w2T, 4096, 1024);
    } else {
        rot = (bf16*)alloc(szW1 * 2);   // largest slice; stream order serializes reuse
    }
    w5_kernel<<<(OO * DD) / 256, 256, 0, stream>>>(Wout, w5T);

    // ---------------- context pass: 64 batches x 16 tokens ----------------
    stats_ctx_kernel<<<B2, 64, 0, stream>>>(x, ctx_mu, ctx_sg, ispos, normed);
    {
        const int R = B2 * NPATCH;   // 1024 rows
        embed_kernel<<<R, 256, 0, stream>>>(normed, W_in, b_in, hdd);
        for (int l = 0; l < LL; l++) {
            bf16* kc = kcache + l * cache_l;
            bf16* vc = vcache + l * cache_l;
            layernorm_kernel<<<R / 4, 256, 0, stream>>>(hdd, xn, ln1_s + l * DD);
            bf16* bq;
            if (big) bq = wqkvT + l * szQKV;
            else { transpose_w<<<dim3(96, 32, 1), 256, 0, stream>>>(Wqkv + l * szQKV, rot, 1024, 3072); bq = rot; }
            hgemm<64, 128, 3><<<dim3(24, 16, 1), 256, 0, stream>>>(xn, bq, qb, nullptr, kc, vc,
                                                                   R, 3072, 1024, 1024, NPATCH, 0);
            attn_kernel<<<B2 * HH * NPATCH / 4, 256, 0, stream>>>(qb, kc, vc, attnb, NPATCH, 0);
            bf16* bo;
            if (big) bo = woT + l * szWO;
            else { transpose_w<<<dim3(32, 32, 1), 256, 0, stream>>>(Wo + l * szWO, rot, 1024, 1024); bo = rot; }
            hgemm<64, 64, 2><<<dim3(16, 16, 2), 256, 0, stream>>>(attnb, bo, hdd, nullptr, nullptr, nullptr,
                                                                  R, 1024, 1024, 512, 0, 0);
            layernorm_kernel<<<R / 4, 256, 0, stream>>>(hdd, xn, ln2_s + l * DD);
            bf16* b1;
            if (big) b1 = w1T + l * szW1;
            else { transpose_w<<<dim3(128, 32, 1), 256, 0, stream>>>(W1 + l * szW1, rot, 1024, 4096); b1 = rot; }
            hgemm<64, 128, 1><<<dim3(32, 16, 1), 256, 0, stream>>>(xn, b1, nullptr, ffnb, nullptr, nullptr,
                                                                   R, 4096, 1024, 1024, 0, 0);
            bf16* bw2;
            if (big) bw2 = w2T + l * szW2;
            else { transpose_w<<<dim3(32, 128, 1), 256, 0, stream>>>(W2 + l * szW2, rot, 4096, 1024); bw2 = rot; }
            hgemm<64, 64, 2><<<dim3(16, 16, 4), 256, 0, stream>>>(ffnb, bw2, hdd, nullptr, nullptr, nullptr,
                                                                  R, 1024, 4096, 1024, 0, 0);
        }
        lnout5_kernel<<<B2, 128, 0, stream>>>(hdd, lnf_s, w5T, ctx_mu, ctx_sg, lastc, NPATCH);
    }

    // ---------------- AR pass: 64 batches x 4 tokens ----------------
    stats_ar_kernel<<<B2, 64, 0, stream>>>(lastc, ctx_mu, ctx_sg, nmu, nsg, normed);
    {
        const int R = B2 * MM;       // 256 rows
        embed_kernel<<<R, 256, 0, stream>>>(normed, W_in, b_in, hdd);
        for (int l = 0; l < LL; l++) {
            bf16* kc = kcache + l * cache_l;
            bf16* vc = vcache + l * cache_l;
            layernorm_kernel<<<R / 4, 256, 0, stream>>>(hdd, xn, ln1_s + l * DD);
            bf16* bq;
            if (big) bq = wqkvT + l * szQKV;
            else { transpose_w<<<dim3(96, 32, 1), 256, 0, stream>>>(Wqkv + l * szQKV, rot, 1024, 3072); bq = rot; }
            hgemm<32, 64, 3><<<dim3(48, 8, 1), 256, 0, stream>>>(xn, bq, qb, nullptr, kc, vc,
                                                                 R, 3072, 1024, 1024, MM, NPATCH);
            attn_kernel<<<B2 * HH * MM / 4, 256, 0, stream>>>(qb, kc, vc, attnb, MM, NPATCH);
            bf16* bo;
            if (big) bo = woT + l * szWO;
            else { transpose_w<<<dim3(32, 32, 1), 256, 0, stream>>>(Wo + l * szWO, rot, 1024, 1024); bo = rot; }
            hgemm<32, 64, 2><<<dim3(16, 8, 2), 256, 0, stream>>>(attnb, bo, hdd, nullptr, nullptr, nullptr,
                                                                 R, 1024, 1024, 512, 0, 0);
            layernorm_kernel<<<R / 4, 256, 0, stream>>>(hdd, xn, ln2_s + l * DD);
            bf16* b1;
            if (big) b1 = w1T + l * szW1;
            else { transpose_w<<<dim3(128, 32, 1), 256, 0, stream>>>(W1 + l * szW1, rot, 1024, 4096); b1 = rot; }
            hgemm<32, 128, 1><<<dim3(32, 8, 1), 256, 0, stream>>>(xn, b1, nullptr, ffnb, nullptr, nullptr,
                                                                  R, 4096, 1024, 1024, 0, 0);
            bf16* bw2;
            if (big) bw2 = w2T + l * szW2;
            else { transpose_w<<<dim3(32, 128, 1), 256, 0, stream>>>(W2 + l * szW2, rot, 4096, 1024); bw2 = rot; }
            hgemm<32, 64, 2><<<dim3(16, 8, 4), 256, 0, stream>>>(ffnb, bw2, hdd, nullptr, nullptr, nullptr,
                                                                 R, 1024, 4096, 1024, 0, 0);
        }
        lnout5_kernel<<<B2, 128, 0, stream>>>(hdd, lnf_s, w5T, nmu, nsg, lasta, MM);
    }

    // ---------------- combine +x / -x and emit ----------------
    combine_kernel<<<(32 * 256) / 256, 256, 0, stream>>>(lastc, lasta, ispos, out);
}

// Round 6
// 1677.900 us; speedup vs baseline: 1.1300x; 1.1300x over previous
//
#include <hip/hip_runtime.h>
#include <hip/hip_bf16.h>
#include <math.h>

// Model constants
#define PP 32      // patch
#define OO 128     // outputs per patch
#define QQ 10      // quantiles
#define MM 4       // AR patches per step
#define LL 8       // layers
#define HH 16      // heads
#define HD 64      // head dim
#define DD 1024    // D = H*HD
#define DFF 4096
#define NPATCH 16  // context patches (512/32)
#define B2 64      // 32 batches x {+x, -x}
#define CMAX 20    // max cache length
#define EPSF 1e-6f

typedef __attribute__((ext_vector_type(8))) short s16x8;   // 8 bf16 (4 VGPRs)
typedef __attribute__((ext_vector_type(4))) float f32x4;   // MFMA accumulator
typedef __hip_bfloat16 bf16;

__device__ inline float b2f(short u)
{
    return __uint_as_float(((unsigned)(unsigned short)u) << 16);
}

// Async global->LDS, 16 B per lane. LDS dest = wave-uniform base + lane*16.
__device__ inline void ld_lds16(void* lds_base, const void* gaddr)
{
    __builtin_amdgcn_global_load_lds(
        (const __attribute__((address_space(1))) unsigned int*)gaddr,
        (__attribute__((address_space(3))) unsigned int*)lds_base, 16, 0, 0);
}

// ---------------------------------------------------------------------------
// Running stats (Chan update), context: 16 patches from scratch. Also is_pos.
__global__ void stats_ctx_kernel(const float* __restrict__ x, float* __restrict__ ctx_mu,
                                 float* __restrict__ ctx_sg, float* __restrict__ ispos,
                                 float* __restrict__ normed)
{
    int b2 = blockIdx.x;            // 0..63
    int tid = threadIdx.x;          // 64
    float sign = (b2 < 32) ? 1.f : -1.f;
    const float* xp = x + (size_t)(b2 & 31) * 512;
    __shared__ float smu[NPATCH], ssg[NPATCH];
    if (tid == 0) {
        float n = 0.f, mu = 0.f, sg = 0.f;
        for (int t = 0; t < NPATCH; t++) {
            float s1 = 0.f;
            for (int p = 0; p < PP; p++) s1 += sign * xp[t * PP + p];
            float nn2 = n + 32.f;
            float nmu_ = (n * mu + s1) / nn2;
            float m2 = n * sg * sg;
            for (int p = 0; p < PP; p++) {
                float xv = sign * xp[t * PP + p];
                m2 += (xv - mu) * (xv - nmu_);
            }
            sg = sqrtf(fmaxf(m2 / nn2, 1e-12f));
            mu = nmu_; n = nn2;
            smu[t] = mu; ssg[t] = sg;
            ctx_mu[b2 * NPATCH + t] = mu;
            ctx_sg[b2 * NPATCH + t] = sg;
        }
        if (b2 < 32) {
            int ok = 1;
            for (int i = 0; i < 512; i++) if (xp[i] < 0.f) ok = 0;
            ispos[b2] = (float)ok;
        }
    }
    __syncthreads();
    for (int i = tid; i < 512; i += 64) {
        int t = i >> 5;
        normed[(size_t)b2 * 512 + i] = (sign * xp[i] - smu[t]) / (ssg[t] + EPSF);
    }
}

// AR stats: continue from n=512 state with 4 new patches (= last 128 preds).
__global__ void stats_ar_kernel(const float* __restrict__ lastc, const float* __restrict__ ctx_mu,
                                const float* __restrict__ ctx_sg, float* __restrict__ nmu,
                                float* __restrict__ nsg, float* __restrict__ normed)
{
    int b2 = blockIdx.x;
    int tid = threadIdx.x;
    __shared__ float smu[MM], ssg[MM];
    const float* xp = lastc + (size_t)b2 * 128;
    if (tid == 0) {
        float n = 512.f;
        float mu = ctx_mu[b2 * NPATCH + 15];
        float sg = ctx_sg[b2 * NPATCH + 15];
        for (int t = 0; t < MM; t++) {
            float s1 = 0.f;
            for (int p = 0; p < PP; p++) s1 += xp[t * PP + p];
            float nn2 = n + 32.f;
            float nmu_ = (n * mu + s1) / nn2;
            float m2 = n * sg * sg;
            for (int p = 0; p < PP; p++) {
                float xv = xp[t * PP + p];
                m2 += (xv - mu) * (xv - nmu_);
            }
            sg = sqrtf(fmaxf(m2 / nn2, 1e-12f));
            mu = nmu_; n = nn2;
            smu[t] = mu; ssg[t] = sg;
            nmu[b2 * MM + t] = mu;
            nsg[b2 * MM + t] = sg;
        }
    }
    __syncthreads();
    for (int i = tid; i < 128; i += 64) {
        int t = i >> 5;
        normed[(size_t)b2 * 128 + i] = (xp[i] - smu[t]) / (ssg[t] + EPSF);
    }
}

// ---------------------------------------------------------------------------
// Embedding: hdd[row, :] = normed[row, 0:32] @ W_in[0:32, :] + b_in   (fp32)
__global__ __launch_bounds__(256) void embed_kernel(const float* __restrict__ normed,
                                                    const float* __restrict__ Win,
                                                    const float* __restrict__ bin,
                                                    float* __restrict__ hdd)
{
    int row = blockIdx.x;
    int tid = threadIdx.x;
    __shared__ float p[PP];
    if (tid < PP) p[tid] = normed[(size_t)row * PP + tid];
    __syncthreads();
    for (int c = tid; c < DD; c += 256) {
        float s = bin[c];
        for (int k = 0; k < PP; k++) s = fmaf(p[k], Win[k * DD + c], s);
        hdd[(size_t)row * DD + c] = s;
    }
}

// ---------------------------------------------------------------------------
// LayerNorm: wave-per-row, fp32 in -> bf16 out. Grid = R/4 blocks of 256.
__global__ __launch_bounds__(256) void layernorm_kernel(const float* __restrict__ in,
                                                        bf16* __restrict__ out,
                                                        const float* __restrict__ scale)
{
    int wave = threadIdx.x >> 6, lane = threadIdx.x & 63;
    size_t row = (size_t)blockIdx.x * 4 + wave;
    const float* x = in + row * DD + lane * 16;
    float e[16];
    #pragma unroll
    for (int j = 0; j < 4; j++) {
        float4 t = ((const float4*)x)[j];
        e[4 * j] = t.x; e[4 * j + 1] = t.y; e[4 * j + 2] = t.z; e[4 * j + 3] = t.w;
    }
    float s = 0.f;
    #pragma unroll
    for (int i = 0; i < 16; i++) s += e[i];
    #pragma unroll
    for (int o = 32; o > 0; o >>= 1) s += __shfl_xor(s, o, 64);
    float m = s * (1.f / 1024.f);
    float vv = 0.f;
    #pragma unroll
    for (int i = 0; i < 16; i++) { float d = e[i] - m; vv = fmaf(d, d, vv); }
    #pragma unroll
    for (int o = 32; o > 0; o >>= 1) vv += __shfl_xor(vv, o, 64);
    float inv = rsqrtf(vv * (1.f / 1024.f) + EPSF);
    const float* sc = scale + lane * 16;
    union { bf16 b[16]; s16x8 v2[2]; } ob;
    #pragma unroll
    for (int j = 0; j < 4; j++) {
        float4 t = ((const float4*)sc)[j];
        ob.b[4 * j]     = __float2bfloat16((e[4 * j]     - m) * inv * t.x);
        ob.b[4 * j + 1] = __float2bfloat16((e[4 * j + 1] - m) * inv * t.y);
        ob.b[4 * j + 2] = __float2bfloat16((e[4 * j + 2] - m) * inv * t.z);
        ob.b[4 * j + 3] = __float2bfloat16((e[4 * j + 3] - m) * inv * t.w);
    }
    s16x8* op = (s16x8*)(out + row * DD + lane * 16);
    op[0] = ob.v2[0]; op[1] = ob.v2[1];
}

// ---------------------------------------------------------------------------
// Weight transpose: fp32 [R][C] (layer blockIdx.z) -> bf16 [C][R]
__global__ __launch_bounds__(256) void transpose_w(const float* __restrict__ in,
                                                   bf16* __restrict__ out,
                                                   int R, int C)
{
    __shared__ float t[32][33];
    size_t base = (size_t)blockIdx.z * R * C;
    int c0 = blockIdx.x * 32, r0 = blockIdx.y * 32;
    int tx = threadIdx.x & 31, ty = threadIdx.x >> 5;  // 32 x 8
    #pragma unroll
    for (int s = 0; s < 4; s++)
        t[ty + 8 * s][tx] = in[base + (size_t)(r0 + ty + 8 * s) * C + c0 + tx];
    __syncthreads();
    #pragma unroll
    for (int s = 0; s < 4; s++)
        out[base + (size_t)(c0 + ty + 8 * s) * R + r0 + tx] = __float2bfloat16(t[tx][ty + 8 * s]);
}

// Gather Wout quantile-5 columns: w5T[o][k] = Wout[k][o*10+5], bf16
__global__ void w5_kernel(const float* __restrict__ Wout, bf16* __restrict__ w5T)
{
    int i = blockIdx.x * 256 + threadIdx.x;   // 128*1024
    int o = i >> 10, k = i & 1023;
    w5T[i] = __float2bfloat16(Wout[(size_t)k * (OO * QQ) + o * QQ + 5]);
}

// ---------------------------------------------------------------------------
__device__ inline float gelu_tanh(float x)
{
    float x3 = x * x * x;
    float t = tanhf(0.7978845608028654f * (x + 0.044715f * x3));
    return 0.5f * x * (1.f + t);
}

// bf16 MFMA GEMM, templated BK (128 or 256), single-buffered, XOR-swizzled
// LDS: slot g at row r holds global granule g^(r&7); read applies the same
// involution -> 2 lanes/16B-slot (free). C[M,N] = A[M,K] @ BT[N,K]^T.
// BK=256 halves the barrier-stall pairs where LDS/occupancy permits.
// Requires Kpart % BK == 0.
// EP: 0 = store fp32 (atomicAdd if gridDim.z>1); 1 = gelu -> bf16;
//     2 = atomicAdd (residual); 3 = QKV: cols<DD -> fp32 Q (stride DD),
//         else bf16 direct into K/V caches (requires gridDim.z==1).
template<int BM, int BN, int BK, int EP>
__global__ __launch_bounds__(256) void hgemm(const bf16* __restrict__ A,
                                             const bf16* __restrict__ BT,
                                             float* __restrict__ C,
                                             bf16* __restrict__ Cbf,
                                             bf16* __restrict__ Kc,
                                             bf16* __restrict__ Vc,
                                             int M, int N, int K, int Kpart,
                                             int nn, int koff)
{
    constexpr int FM = BM / 32 > 0 ? BM / 32 : 1;   // BM=32 -> FM=1
    constexpr int FN = BN / 32;
    constexpr int GPR = BK / 8;        // 16B granules per row
    constexpr int RPC = 64 / GPR;      // rows per 1KB wave-load (4 @128, 2 @256)
    __shared__ __align__(16) short As[BM * BK];
    __shared__ __align__(16) short Bs[BN * BK];
    int tid = threadIdx.x;
    int lane = tid & 63, wave = tid >> 6;
    int wm = (wave >> 1) * (BM / 2), wn = (wave & 1) * (BN / 2);
    int lm = lane & 15, quad = lane >> 4;
    int row0 = blockIdx.y * BM, col0 = blockIdx.x * BN;
    int kb = blockIdx.z * Kpart, ke = kb + Kpart;
    int rr = lane / GPR;                   // row within chunk
    int gcol = lane % GPR;                 // granule column
    int key = (wave * RPC + rr) & 7;       // == (chunk_row & 7), c-independent
    int gsw = (gcol ^ key) * 8;            // pre-swizzled source k-offset (shorts)
    int swz = lm & 7;                      // read-side row swizzle key

    f32x4 ac[FM][FN];
    #pragma unroll
    for (int i = 0; i < FM; i++)
        #pragma unroll
        for (int j = 0; j < FN; j++) ac[i][j] = (f32x4){0.f, 0.f, 0.f, 0.f};

    for (int k0 = kb; k0 < ke; k0 += BK) {
        #pragma unroll
        for (int c = 0; c < BM / (RPC * 4); c++) {
            int ch = wave + 4 * c;    // RPC rows, 1 KB per wave
            ld_lds16(&As[ch * 512], A + (size_t)(row0 + ch * RPC + rr) * K + k0 + gsw);
        }
        #pragma unroll
        for (int c = 0; c < BN / (RPC * 4); c++) {
            int ch = wave + 4 * c;
            ld_lds16(&Bs[ch * 512], BT + (size_t)(col0 + ch * RPC + rr) * K + k0 + gsw);
        }
        __syncthreads();              // drains vmcnt (async LDS) before reads
        #pragma unroll
        for (int kk = 0; kk < BK / 32; kk++) {
            int gq = ((kk * 4 + quad) ^ swz) * 8;
            s16x8 af[FM], bfr[FN];
            #pragma unroll
            for (int i = 0; i < FM; i++) af[i] = *(const s16x8*)&As[(wm + i * 16 + lm) * BK + gq];
            #pragma unroll
            for (int j = 0; j < FN; j++) bfr[j] = *(const s16x8*)&Bs[(wn + j * 16 + lm) * BK + gq];
            #pragma unroll
            for (int i = 0; i < FM; i++)
                #pragma unroll
                for (int j = 0; j < FN; j++)
                    ac[i][j] = __builtin_amdgcn_mfma_f32_16x16x32_bf16(af[i], bfr[j], ac[i][j], 0, 0, 0);
        }
        __syncthreads();
    }
    bool multi = (gridDim.z > 1);
    #pragma unroll
    for (int i = 0; i < FM; i++) {
        #pragma unroll
        for (int j = 0; j < FN; j++) {
            #pragma unroll
            for (int r = 0; r < 4; r++) {
                int rr2 = row0 + wm + i * 16 + quad * 4 + r;
                int cc = col0 + wn + j * 16 + lm;
                float v = ac[i][j][r];
                if (EP == 0) {
                    size_t idx = (size_t)rr2 * N + cc;
                    if (multi) atomicAdd(&C[idx], v); else C[idx] = v;
                } else if (EP == 1) {
                    Cbf[(size_t)rr2 * N + cc] = __float2bfloat16(gelu_tanh(v));
                } else if (EP == 2) {
                    atomicAdd(&C[(size_t)rr2 * N + cc], v);
                } else {
                    // QKV fused scatter (tile is uniformly Q, K, or V: 1024%BN==0)
                    if (cc < DD) {
                        C[(size_t)rr2 * DD + cc] = v;         // Q, fp32, stride DD
                    } else {
                        int col = cc & (DD - 1);
                        int b = rr2 / nn, n = rr2 - b * nn;
                        int h = col >> 6, hd_ = col & 63;
                        size_t dst = (((size_t)(b * HH + h)) * CMAX + koff + n) * HD + hd_;
                        if (cc < 2 * DD) Kc[dst] = __float2bfloat16(v);
                        else             Vc[dst] = __float2bfloat16(v);
                    }
                }
            }
        }
    }
}

// ---------------------------------------------------------------------------
// Attention: 4 waves per block, one (b,h,n) task per wave. Causal over
// len = n + off + 1 cache rows. Q fp32, row stride DD.
__global__ __launch_bounds__(256) void attn_kernel(const float* __restrict__ qb,
                                                   const bf16* __restrict__ Kc,
                                                   const bf16* __restrict__ Vc,
                                                   bf16* __restrict__ outb, int Nn, int off)
{
    int wave = threadIdx.x >> 6, lane = threadIdx.x & 63;
    int gid = blockIdx.x * 4 + wave;
    int n = gid % Nn;
    int h = (gid / Nn) & (HH - 1);
    int b = gid / (Nn * HH);
    int len = n + off + 1;
    const float* q = qb + ((size_t)(b * Nn + n)) * DD + h * HD;
    const bf16* Kb = Kc + ((size_t)(b * HH + h)) * CMAX * HD;
    const bf16* Vb = Vc + ((size_t)(b * HH + h)) * CMAX * HD;

    __shared__ float sq[4][64];
    __shared__ float satt[4][64];
    sq[wave][lane] = q[lane];
    __syncthreads();

    float score = -1e30f;
    if (lane < len) {
        const s16x8* kr8 = (const s16x8*)(Kb + lane * HD);
        float s = 0.f;
        #pragma unroll
        for (int c = 0; c < 8; c++) {
            s16x8 kv = kr8[c];
            #pragma unroll
            for (int j = 0; j < 8; j++) s = fmaf(sq[wave][c * 8 + j], b2f(kv[j]), s);
        }
        score = s * 0.125f;   // 1/sqrt(64)
    }
    float mx = score;
    for (int o = 32; o > 0; o >>= 1) mx = fmaxf(mx, __shfl_xor(mx, o, 64));
    float e = (lane < len) ? expf(score - mx) : 0.f;
    float sm = e;
    for (int o = 32; o > 0; o >>= 1) sm += __shfl_xor(sm, o, 64);
    satt[wave][lane] = e / sm;
    __syncthreads();
    float acc = 0.f;
    for (int m = 0; m < len; m++) acc = fmaf(satt[wave][m], __bfloat162float(Vb[m * HD + lane]), acc);
    outb[((size_t)(b * Nn + n)) * DD + h * HD + lane] = __float2bfloat16(acc);
}

// ---------------------------------------------------------------------------
// Fused final LN + quantile-5 head + revin. Only the LAST row per b2 is
// consumed downstream, so LN runs on 64 rows instead of R. One block per b2.
__global__ __launch_bounds__(128) void lnout5_kernel(const float* __restrict__ hdd,
                                                     const float* __restrict__ lnf,
                                                     const bf16* __restrict__ w5T,
                                                     const float* __restrict__ mus,
                                                     const float* __restrict__ sgs,
                                                     float* __restrict__ last, int Nn)
{
    int b2 = blockIdx.x, tid = threadIdx.x;
    const float* x = hdd + (size_t)(b2 * Nn + Nn - 1) * DD;
    __shared__ float sx[DD];
    __shared__ float red[128];
    float s = 0.f;
    for (int i = tid; i < DD; i += 128) s += x[i];
    red[tid] = s; __syncthreads();
    for (int st = 64; st > 0; st >>= 1) { if (tid < st) red[tid] += red[tid + st]; __syncthreads(); }
    float m = red[0] * (1.f / 1024.f);
    __syncthreads();
    float vv = 0.f;
    for (int i = tid; i < DD; i += 128) { float d = x[i] - m; vv = fmaf(d, d, vv); }
    red[tid] = vv; __syncthreads();
    for (int st = 64; st > 0; st >>= 1) { if (tid < st) red[tid] += red[tid + st]; __syncthreads(); }
    float inv = rsqrtf(red[0] * (1.f / 1024.f) + EPSF);
    __syncthreads();
    for (int i = tid; i < DD; i += 128) sx[i] = (x[i] - m) * inv * lnf[i];
    __syncthreads();
    const s16x8* w8 = (const s16x8*)(w5T + (size_t)tid * DD);
    float acc = 0.f;
    for (int k = 0; k < DD / 8; k++) {
        s16x8 wv = w8[k];
        #pragma unroll
        for (int j = 0; j < 8; j++) acc = fmaf(sx[k * 8 + j], b2f(wv[j]), acc);
    }
    float mu = mus[b2 * Nn + (Nn - 1)];
    float sg = sgs[b2 * Nn + (Nn - 1)];
    last[(size_t)b2 * 128 + tid] = acc * (sg + EPSF) + mu;
}

// ---------------------------------------------------------------------------
// Combine +x / -x halves, clamp if all-positive input, emit FLOAT32.
__global__ void combine_kernel(const float* __restrict__ lastc, const float* __restrict__ lasta,
                               const float* __restrict__ ispos, float* __restrict__ out)
{
    int i = blockIdx.x * 256 + threadIdx.x;   // 8192
    int b = i >> 8, t = i & 255;
    float a, an;
    if (t < 128) { a = lastc[b * 128 + t];        an = lastc[(b + 32) * 128 + t]; }
    else         { a = lasta[b * 128 + t - 128];  an = lasta[(b + 32) * 128 + t - 128]; }
    float raw = (a - an) * 0.5f;
    if (ispos[b] > 0.5f) raw = fmaxf(raw, 0.f);
    out[i] = raw;
}

// ---------------------------------------------------------------------------
extern "C" void kernel_launch(void* const* d_in, const int* in_sizes, int n_in,
                              void* d_out, int out_size, void* d_ws, size_t ws_size,
                              hipStream_t stream)
{
    (void)in_sizes; (void)n_in; (void)out_size;
    const float* x     = (const float*)d_in[0];
    const float* W_in  = (const float*)d_in[1];
    const float* b_in  = (const float*)d_in[2];
    const float* ln1_s = (const float*)d_in[3];
    const float* Wqkv  = (const float*)d_in[4];   // (8,1024,3072)
    const float* Wo    = (const float*)d_in[5];   // (8,1024,1024)
    const float* ln2_s = (const float*)d_in[6];
    const float* W1    = (const float*)d_in[7];   // (8,1024,4096)
    const float* W2    = (const float*)d_in[8];   // (8,4096,1024)
    const float* lnf_s = (const float*)d_in[9];
    const float* Wout  = (const float*)d_in[10];  // (1024,1280)
    float* out = (float*)d_out;

    size_t off = 0;
    auto alloc = [&](size_t bytes) {
        char* p = (char*)d_ws + off;
        off = (off + bytes + 255) & ~(size_t)255;
        return (void*)p;
    };
    float* ctx_mu = (float*)alloc(B2 * NPATCH * 4);
    float* ctx_sg = (float*)alloc(B2 * NPATCH * 4);
    float* nmu    = (float*)alloc(B2 * MM * 4);
    float* nsg    = (float*)alloc(B2 * MM * 4);
    float* ispos  = (float*)alloc(32 * 4);
    float* normed = (float*)alloc(B2 * NPATCH * PP * 4);
    float* lastc  = (float*)alloc(B2 * 128 * 4);
    float* lasta  = (float*)alloc(B2 * 128 * 4);
    float* hdd    = (float*)alloc((size_t)B2 * NPATCH * DD * 4);
    float* qb     = (float*)alloc((size_t)B2 * NPATCH * DD * 4);   // Q only, fp32
    bf16* xn      = (bf16*)alloc((size_t)B2 * NPATCH * DD * 2);
    bf16* attnb   = (bf16*)alloc((size_t)B2 * NPATCH * DD * 2);
    bf16* ffnb    = (bf16*)alloc((size_t)B2 * NPATCH * DFF * 2);
    const size_t cache_l = (size_t)B2 * HH * CMAX * HD;
    bf16* kcache  = (bf16*)alloc(LL * cache_l * 2);
    bf16* vcache  = (bf16*)alloc(LL * cache_l * 2);
    bf16* w5T     = (bf16*)alloc((size_t)OO * DD * 2);

    const size_t szQKV = (size_t)DD * 3 * DD;     // per-layer elems
    const size_t szWO  = (size_t)DD * DD;
    const size_t szW1  = (size_t)DD * DFF;
    const size_t szW2  = (size_t)DFF * DD;
    const size_t WBYTES = (szQKV + szWO + szW1 + szW2) * LL * 2 + 4096;
    bool big = (off + WBYTES) <= ws_size;

    bf16 *wqkvT = nullptr, *woT = nullptr, *w1T = nullptr, *w2T = nullptr, *rot = nullptr;
    if (big) {
        wqkvT = (bf16*)alloc(LL * szQKV * 2);
        woT   = (bf16*)alloc(LL * szWO * 2);
        w1T   = (bf16*)alloc(LL * szW1 * 2);
        w2T   = (bf16*)alloc(LL * szW2 * 2);
        transpose_w<<<dim3(3072 / 32, 1024 / 32, LL), 256, 0, stream>>>(Wqkv, wqkvT, 1024, 3072);
        transpose_w<<<dim3(1024 / 32, 1024 / 32, LL), 256, 0, stream>>>(Wo, woT, 1024, 1024);
        transpose_w<<<dim3(4096 / 32, 1024 / 32, LL), 256, 0, stream>>>(W1, w1T, 1024, 4096);
        transpose_w<<<dim3(1024 / 32, 4096 / 32, LL), 256, 0, stream>>>(W2, w2T, 4096, 1024);
    } else {
        rot = (bf16*)alloc(szW1 * 2);   // largest slice; stream order serializes reuse
    }
    w5_kernel<<<(OO * DD) / 256, 256, 0, stream>>>(Wout, w5T);

    // ---------------- context pass: 64 batches x 16 tokens ----------------
    stats_ctx_kernel<<<B2, 64, 0, stream>>>(x, ctx_mu, ctx_sg, ispos, normed);
    {
        const int R = B2 * NPATCH;   // 1024 rows
        embed_kernel<<<R, 256, 0, stream>>>(normed, W_in, b_in, hdd);
        for (int l = 0; l < LL; l++) {
            bf16* kc = kcache + l * cache_l;
            bf16* vc = vcache + l * cache_l;
            layernorm_kernel<<<R / 4, 256, 0, stream>>>(hdd, xn, ln1_s + l * DD);
            bf16* bq;
            if (big) bq = wqkvT + l * szQKV;
            else { transpose_w<<<dim3(96, 32, 1), 256, 0, stream>>>(Wqkv + l * szQKV, rot, 1024, 3072); bq = rot; }
            hgemm<64, 128, 128, 3><<<dim3(24, 16, 1), 256, 0, stream>>>(xn, bq, qb, nullptr, kc, vc,
                                                                        R, 3072, 1024, 1024, NPATCH, 0);
            attn_kernel<<<B2 * HH * NPATCH / 4, 256, 0, stream>>>(qb, kc, vc, attnb, NPATCH, 0);
            bf16* bo;
            if (big) bo = woT + l * szWO;
            else { transpose_w<<<dim3(32, 32, 1), 256, 0, stream>>>(Wo + l * szWO, rot, 1024, 1024); bo = rot; }
            hgemm<64, 64, 256, 2><<<dim3(16, 16, 2), 256, 0, stream>>>(attnb, bo, hdd, nullptr, nullptr, nullptr,
                                                                       R, 1024, 1024, 512, 0, 0);
            layernorm_kernel<<<R / 4, 256, 0, stream>>>(hdd, xn, ln2_s + l * DD);
            bf16* b1;
            if (big) b1 = w1T + l * szW1;
            else { transpose_w<<<dim3(128, 32, 1), 256, 0, stream>>>(W1 + l * szW1, rot, 1024, 4096); b1 = rot; }
            hgemm<64, 128, 128, 1><<<dim3(32, 16, 1), 256, 0, stream>>>(xn, b1, nullptr, ffnb, nullptr, nullptr,
                                                                        R, 4096, 1024, 1024, 0, 0);
            bf16* bw2;
            if (big) bw2 = w2T + l * szW2;
            else { transpose_w<<<dim3(32, 128, 1), 256, 0, stream>>>(W2 + l * szW2, rot, 4096, 1024); bw2 = rot; }
            hgemm<64, 64, 128, 2><<<dim3(16, 16, 4), 256, 0, stream>>>(ffnb, bw2, hdd, nullptr, nullptr, nullptr,
                                                                       R, 1024, 4096, 1024, 0, 0);
        }
        lnout5_kernel<<<B2, 128, 0, stream>>>(hdd, lnf_s, w5T, ctx_mu, ctx_sg, lastc, NPATCH);
    }

    // ---------------- AR pass: 64 batches x 4 tokens ----------------
    stats_ar_kernel<<<B2, 64, 0, stream>>>(lastc, ctx_mu, ctx_sg, nmu, nsg, normed);
    {
        const int R = B2 * MM;       // 256 rows
        embed_kernel<<<R, 256, 0, stream>>>(normed, W_in, b_in, hdd);
        for (int l = 0; l < LL; l++) {
            bf16* kc = kcache + l * cache_l;
            bf16* vc = vcache + l * cache_l;
            layernorm_kernel<<<R / 4, 256, 0, stream>>>(hdd, xn, ln1_s + l * DD);
            bf16* bq;
            if (big) bq = wqkvT + l * szQKV;
            else { transpose_w<<<dim3(96, 32, 1), 256, 0, stream>>>(Wqkv + l * szQKV, rot, 1024, 3072); bq = rot; }
            hgemm<32, 64, 256, 3><<<dim3(48, 8, 1), 256, 0, stream>>>(xn, bq, qb, nullptr, kc, vc,
                                                                      R, 3072, 1024, 1024, MM, NPATCH);
            attn_kernel<<<B2 * HH * MM / 4, 256, 0, stream>>>(qb, kc, vc, attnb, MM, NPATCH);
            bf16* bo;
            if (big) bo = woT + l * szWO;
            else { transpose_w<<<dim3(32, 32, 1), 256, 0, stream>>>(Wo + l * szWO, rot, 1024, 1024); bo = rot; }
            hgemm<32, 64, 256, 2><<<dim3(16, 8, 2), 256, 0, stream>>>(attnb, bo, hdd, nullptr, nullptr, nullptr,
                                                                      R, 1024, 1024, 512, 0, 0);
            layernorm_kernel<<<R / 4, 256, 0, stream>>>(hdd, xn, ln2_s + l * DD);
            bf16* b1;
            if (big) b1 = w1T + l * szW1;
            else { transpose_w<<<dim3(128, 32, 1), 256, 0, stream>>>(W1 + l * szW1, rot, 1024, 4096); b1 = rot; }
            hgemm<32, 128, 256, 1><<<dim3(32, 8, 1), 256, 0, stream>>>(xn, b1, nullptr, ffnb, nullptr, nullptr,
                                                                       R, 4096, 1024, 1024, 0, 0);
            bf16* bw2;
            if (big) bw2 = w2T + l * szW2;
            else { transpose_w<<<dim3(32, 128, 1), 256, 0, stream>>>(W2 + l * szW2, rot, 4096, 1024); bw2 = rot; }
            hgemm<32, 64, 256, 2><<<dim3(16, 8, 4), 256, 0, stream>>>(ffnb, bw2, hdd, nullptr, nullptr, nullptr,
                                                                      R, 1024, 4096, 1024, 0, 0);
        }
        lnout5_kernel<<<B2, 128, 0, stream>>>(hdd, lnf_s, w5T, nmu, nsg, lasta, MM);
    }

    // ---------------- combine +x / -x and emit ----------------
    combine_kernel<<<(32 * 256) / 256, 256, 0, stream>>>(lastc, lasta, ispos, out);
}